// Round 11
// baseline (309.795 us; speedup 1.0000x reference)
//
#include <hip/hip_runtime.h>
#include <hip/hip_bf16.h>

#define TOK 4096
#define DIM 1024
#define HID 2048
#define LN10K 9.210340371976184f

typedef __bf16 bh;
typedef __bf16 v8bf __attribute__((ext_vector_type(8)));
typedef float v4f __attribute__((ext_vector_type(4)));

typedef const __attribute__((address_space(1))) void* gvp;
typedef __attribute__((address_space(3))) void* svp;

__device__ __forceinline__ void gl_lds16(const bh* g, bh* s) {
  __builtin_amdgcn_global_load_lds((gvp)g, (svp)s, 16, 0, 0);
}

// Journal:
// r6:  XCD remap REGRESSED (FETCH 76->145MB). Raw id order already good.
// r8:  dispatch merge 8->6 = +10.7us (launch-gap theory CONFIRMED). BEST.
// r9:  transposes inside D3/D4 REGRESSED (-9us): extra blocks on the
//      critical path of serial dispatches. Reverted.
// r10: ONE cooperative mega-kernel (grid.sync between phases) KILLED the
//      harness (container failed twice — hipLaunchCooperativeKernel is not
//      compatible with this harness's graph capture). Do not retry.
//      Remaining dispatch boundaries all carry true data dependencies.
// r11: exact r8 restore (best verified state, 297.08us).

// ---------------- GEMM body: C = act(A @ BT^T + bias), 16x16x32 MFMA -------
// m97-canonical config: 256 threads = 4 waves (2x2), block tile 128 x BN,
// BK=64, wave tile 64 x (BN/2), acc[4][BN/32] (64 VGPR at BN=128).
// Staging ledger: one gl_lds16 x 256 thr = 2048 bh = 32 rows of 64 cols;
// A tile 128 rows -> 4 calls; B tile BN rows -> BN/32 calls.
// EXPS: epilogue stores exp(score) + fp32 rowsum atomics.
// TROUT: epilogue transposes the 64x128 C-tile through LDS (reuses As)
// and stores coalesced 16B row segments.
template <int BN, bool RELU, bool TROUT, bool EXPS, typename OutT>
__device__ __forceinline__ void gemm_bt_body(int id,
                                             const bh* __restrict__ A,
                                             const bh* __restrict__ BT,
                                             const float* __restrict__ bias,
                                             OutT* __restrict__ C,
                                             float* __restrict__ rowsum,
                                             int K, int lda, int ldbt, int ldc) {
  constexpr int NT = BN / 32;          // n-frags per wave: 4 (BN=128) or 2 (BN=64)
  __shared__ bh As[128 * 64];          // 16 KB
  __shared__ bh Bs[BN * 64];           // 16 or 8 KB
  const int t = threadIdx.x;
  const int bm = (id & 31) * 128, bn = (id >> 5) * BN;

  const int srow = t >> 3;             // staging row-in-group 0..31
  const int c8 = ((t & 7) ^ (srow & 7)) * 8;
  const bh* gA = A + (size_t)(bm + srow) * lda + c8;
  const bh* gB = BT + (size_t)(bn + srow) * ldbt + c8;
  bh* sA = As + t * 8;
  bh* sB = Bs + t * 8;

  const int lane = t & 63, w = t >> 6;
  const int wm = (w >> 1) * 64, wn = (w & 1) * (BN / 2);
  const int lc = lane & 15, q = lane >> 4;

  v4f acc[4][NT] = {};
  for (int k0 = 0; k0 < K; k0 += 64) {
#pragma unroll
    for (int j = 0; j < 4; ++j)
      gl_lds16(gA + k0 + j * 32 * lda, sA + j * 2048);
#pragma unroll
    for (int j = 0; j < BN / 32; ++j)
      gl_lds16(gB + k0 + j * 32 * ldbt, sB + j * 2048);
    __syncthreads();
#pragma unroll
    for (int h = 0; h < 2; ++h) {
      const int off = ((h * 4 + q) ^ (lc & 7)) * 8;
      v8bf af[4], bfr[NT];
#pragma unroll
      for (int mt = 0; mt < 4; ++mt)
        af[mt] = *(const v8bf*)(As + (wm + mt * 16 + lc) * 64 + off);
#pragma unroll
      for (int nt = 0; nt < NT; ++nt)
        bfr[nt] = *(const v8bf*)(Bs + (wn + nt * 16 + lc) * 64 + off);
#pragma unroll
      for (int mt = 0; mt < 4; ++mt)
#pragma unroll
        for (int nt = 0; nt < NT; ++nt)
          acc[mt][nt] = __builtin_amdgcn_mfma_f32_16x16x32_bf16(af[mt], bfr[nt], acc[mt][nt], 0, 0, 0);
    }
    __syncthreads();
  }

  // C/D layout: col = lane&15, row = q*4 + r  (m89-verified)
  const int r4 = q * 4;
  if (EXPS) {
    float bbv[NT];
#pragma unroll
    for (int nt = 0; nt < NT; ++nt)
      bbv[nt] = bias ? bias[bn + wn + nt * 16 + lc] : 0.0f;
#pragma unroll
    for (int mt = 0; mt < 4; ++mt) {
#pragma unroll
      for (int r = 0; r < 4; ++r) {
        int row = bm + wm + mt * 16 + r4 + r;
        float rs = 0.0f;
#pragma unroll
        for (int nt = 0; nt < NT; ++nt) {
          float val = __expf(acc[mt][nt][r] + bbv[nt]);
          rs += val;
          C[(size_t)row * ldc + bn + wn + nt * 16 + lc] = (OutT)val;
        }
        rs += __shfl_xor(rs, 1);
        rs += __shfl_xor(rs, 2);
        rs += __shfl_xor(rs, 4);
        rs += __shfl_xor(rs, 8);
        if (lc == 0) atomicAdd(rowsum + row, rs);
      }
    }
  } else if (TROUT) {
    // transpose 64(col) x 128(row) tile through LDS (reuse As: 8192 bh),
    // then coalesced 16B stores: each output row = 256B contiguous.
    bh* trs = As;  // safe: k-loop ended with __syncthreads after all reads
#pragma unroll
    for (int mt = 0; mt < 4; ++mt) {
#pragma unroll
      for (int nt = 0; nt < NT; ++nt) {
        int cl = wn + nt * 16 + lc;          // 0..63 (BN=64)
        float bb = bias ? bias[bn + cl] : 0.0f;
#pragma unroll
        for (int r = 0; r < 4; ++r) {
          float val = acc[mt][nt][r] + bb;
          if (RELU) val = fmaxf(val, 0.0f);
          trs[cl * 128 + (wm + mt * 16 + r4 + r)] = (bh)val;
        }
      }
    }
    __syncthreads();
#pragma unroll
    for (int p = 0; p < 4; ++p) {
      int chunk = p * 256 + t;               // 0..1023 over 64x128 tile
      int vr = chunk >> 4, sc = chunk & 15;  // row 0..63, 16B seg 0..15
      *(v8bf*)((bh*)C + (size_t)(bn + vr) * ldc + bm + sc * 8) =
          *(const v8bf*)(trs + vr * 128 + sc * 8);
    }
  } else {
#pragma unroll
    for (int mt = 0; mt < 4; ++mt) {
      int row0 = bm + wm + mt * 16 + r4;
#pragma unroll
      for (int nt = 0; nt < NT; ++nt) {
        int col = bn + wn + nt * 16 + lc;
        float bb = bias ? bias[col] : 0.0f;
#pragma unroll
        for (int r = 0; r < 4; ++r) {
          float val = acc[mt][nt][r] + bb;
          if (RELU) val = fmaxf(val, 0.0f);
          C[(size_t)(row0 + r) * ldc + col] = (OutT)val;
        }
      }
    }
  }
}

template <int BN, bool RELU, bool TROUT, bool EXPS, typename OutT>
__global__ __launch_bounds__(256, 2) void gemm_bt(const bh* __restrict__ A,
                                                  const bh* __restrict__ BT,
                                                  const float* __restrict__ bias,
                                                  OutT* __restrict__ C,
                                                  float* __restrict__ rowsum,
                                                  int K, int lda, int ldbt, int ldc) {
  gemm_bt_body<BN, RELU, TROUT, EXPS, OutT>(blockIdx.x, A, BT, bias, C, rowsum,
                                            K, lda, ldbt, ldc);
}

// ---------------- D2: prep_x_colsum U transpose_all (one dispatch) ---------
// blocks 0..511: cast X -> feat left half + colsum(E) partial atomics.
// blocks 512..13823: 32x32 transpose+cast tiles of Wv/W1/W2.
__global__ __launch_bounds__(256) void prep_and_transpose(
    const float* __restrict__ X, bh* __restrict__ featb, float* __restrict__ S,
    const float* __restrict__ Wv, const float* __restrict__ W1,
    const float* __restrict__ W2, bh* __restrict__ WvT, bh* __restrict__ W1T,
    bh* __restrict__ W2T) {
  __shared__ float tile[32][33];
  int bid = blockIdx.x;
  if (bid < 512) {
    // prep_x_colsum (orig grid (2,256) flattened: bx=bid&1, by=bid>>1)
    int cp = (bid & 1) * 256 + threadIdx.x;     // column pair 0..511
    int c = cp * 2;
    int r0 = (bid >> 1) * 16;
    float inv_denom = __expf(-(float)c * (LN10K / (float)DIM));
    float s0 = 0.f, s1 = 0.f;
#pragma unroll 4
    for (int r = r0; r < r0 + 16; ++r) {
      float2 x = *(const float2*)(X + (size_t)r * DIM + c);
      float sn, cs;
      __sincosf((float)r * inv_denom, &sn, &cs);
      s0 += sn * x.x;
      s1 += cs * x.y;
      bh pair[2] = {(bh)x.x, (bh)x.y};
      *(ushort2*)(featb + (size_t)r * (2 * DIM) + c) = *(ushort2*)pair;
    }
    atomicAdd(&S[c], s0);
    atomicAdd(&S[c + 1], s1);
    return;
  }
  bid -= 512;
  const float* in; bh* out; int Ncol, R, bx, by;
  if (bid < 1024)      { in = Wv; out = WvT; Ncol = DIM; R = DIM;
                         bx = bid & 31; by = bid >> 5; }
  else if (bid < 5120) { int b = bid - 1024; in = W1; out = W1T; Ncol = HID; R = 2 * DIM;
                         bx = b & 63; by = b >> 6; }
  else                 { int b = bid - 5120; in = W2; out = W2T; Ncol = TOK; R = HID;
                         bx = b & 127; by = b >> 7; }
  int nb = bx * 32, rb = by * 32;
  int tx = threadIdx.x & 31, ty = threadIdx.x >> 5;   // (32,8) from 256 1D
#pragma unroll
  for (int j = 0; j < 32; j += 8)
    tile[ty + j][tx] = in[(size_t)(rb + ty + j) * Ncol + nb + tx];
  __syncthreads();
#pragma unroll
  for (int j = 0; j < 32; j += 8)
    out[(size_t)(nb + ty + j) * R + rb + tx] = (bh)tile[tx][ty + j];
}

// ---------------- D3: gemm1 (V^T) U prep_loo (one dispatch) ----------------
// blocks 0..511: Vt = (feat_left @ WvT^T + bv)^T  (reads featb LEFT half
// only: staging col = k0 + c8 + j-in-16B <= 1023; WvT from D2).
// blocks 512..4607: loo -> feat RIGHT half (reads S from D2). No overlap.
__global__ __launch_bounds__(256, 2) void gemm1_and_loo(
    const bh* __restrict__ featb, const bh* __restrict__ WvT,
    const float* __restrict__ bv, bh* __restrict__ Vt,
    const float* __restrict__ X, const float* __restrict__ S,
    bh* __restrict__ featb_w) {
  int bid = blockIdx.x;
  if (bid < 512) {
    gemm_bt_body<64, false, true, false, bh>(bid, featb, WvT, bv, Vt, nullptr,
                                             DIM, 2 * DIM, DIM, TOK);
    return;
  }
  // prep_loo
  size_t e4 = ((size_t)(bid - 512) * 256 + threadIdx.x) * 4;  // over TOK*DIM
  int r = (int)(e4 >> 10);
  int c = (int)(e4 & 1023);
  float4 x = *(const float4*)(X + e4);
  float4 s = *(const float4*)(S + c);
  float id0 = __expf(-(float)c * (LN10K / (float)DIM));
  float id1 = __expf(-(float)(c + 2) * (LN10K / (float)DIM));
  float sn0, cs0, sn1, cs1;
  __sincosf((float)r * id0, &sn0, &cs0);
  __sincosf((float)r * id1, &sn1, &cs1);
  const float inv = 1.0f / (float)(TOK - 1);
  bh outv[4];
  outv[0] = (bh)((s.x - sn0 * x.x) * inv);
  outv[1] = (bh)((s.y - cs0 * x.y) * inv);
  outv[2] = (bh)((s.z - sn1 * x.z) * inv);
  outv[3] = (bh)((s.w - cs1 * x.w) * inv);
  *(ushort4*)(featb_w + (size_t)r * (2 * DIM) + DIM + c) = *(ushort4*)outv;
}

// ---------------- gemm4_fused: out = (scr @ V) / rowsum, full-K ------------
// Tile 64x128, BK=64, K=4096. 256 thr = 4 waves (2Mx2N), wave tile 32x64,
// acc[2][4]. Grid 512 blocks = 2/CU. LDS 8KB A + 16KB B.
// Staging ledger: A tile 64 rows -> 2 calls; B tile 128 rows -> 4 calls.
__global__ __launch_bounds__(256, 2) void gemm4_fused(const bh* __restrict__ A,
                                                      const bh* __restrict__ BT,
                                                      const float* __restrict__ rowsum,
                                                      float* __restrict__ out) {
  __shared__ bh As[64 * 64];           // 8 KB
  __shared__ bh Bs[128 * 64];          // 16 KB
  const int t = threadIdx.x;
  const int id = blockIdx.x;           // 512 blocks
  const int bm = (id & 63) * 64, bn = (id >> 6) * 128;

  const int sr = t >> 3;               // 0..31
  const int c8 = ((t & 7) ^ (sr & 7)) * 8;
  const bh* gA = A + (size_t)(bm + sr) * TOK + c8;
  const bh* gB = BT + (size_t)(bn + sr) * TOK + c8;
  bh* sA = As + t * 8;
  bh* sB = Bs + t * 8;

  const int lane = t & 63, w = t >> 6;
  const int wm = (w >> 1) * 32, wn = (w & 1) * 64;
  const int lc = lane & 15, q = lane >> 4;

  v4f acc[2][4] = {};
  for (int k0 = 0; k0 < TOK; k0 += 64) {
#pragma unroll
    for (int j = 0; j < 2; ++j)
      gl_lds16(gA + k0 + (size_t)(j * 32) * TOK, sA + j * 2048);
#pragma unroll
    for (int j = 0; j < 4; ++j)
      gl_lds16(gB + k0 + (size_t)(j * 32) * TOK, sB + j * 2048);
    __syncthreads();
#pragma unroll
    for (int h = 0; h < 2; ++h) {
      const int off = ((h * 4 + q) ^ (lc & 7)) * 8;
      v8bf af[2], bfr[4];
#pragma unroll
      for (int mt = 0; mt < 2; ++mt)
        af[mt] = *(const v8bf*)(As + (wm + mt * 16 + lc) * 64 + off);
#pragma unroll
      for (int nt = 0; nt < 4; ++nt)
        bfr[nt] = *(const v8bf*)(Bs + (wn + nt * 16 + lc) * 64 + off);
#pragma unroll
      for (int mt = 0; mt < 2; ++mt)
#pragma unroll
        for (int nt = 0; nt < 4; ++nt)
          acc[mt][nt] = __builtin_amdgcn_mfma_f32_16x16x32_bf16(af[mt], bfr[nt], acc[mt][nt], 0, 0, 0);
    }
    __syncthreads();
  }

  const int r4 = q * 4;
#pragma unroll
  for (int mt = 0; mt < 2; ++mt) {
#pragma unroll
    for (int r = 0; r < 4; ++r) {
      int row = bm + wm + mt * 16 + r4 + r;
      float inv = 1.0f / rowsum[row];
#pragma unroll
      for (int nt = 0; nt < 4; ++nt)
        out[(size_t)row * DIM + bn + wn + nt * 16 + lc] = acc[mt][nt][r] * inv;
    }
  }
}

extern "C" void kernel_launch(void* const* d_in, const int* in_sizes, int n_in,
                              void* d_out, int out_size, void* d_ws, size_t ws_size,
                              hipStream_t stream) {
  (void)in_sizes; (void)n_in; (void)out_size; (void)ws_size;
  const float* X  = (const float*)d_in[0];
  // d_in[1] = mask, unused by the module
  const float* Wv = (const float*)d_in[2];
  const float* bv = (const float*)d_in[3];
  const float* W1 = (const float*)d_in[4];
  const float* b1 = (const float*)d_in[5];
  const float* W2 = (const float*)d_in[6];
  const float* b2 = (const float*)d_in[7];
  float* out = (float*)d_out;

  char* ws = (char*)d_ws;
  bh* featb = (bh*)(ws);                       // 4096 x 2048 bf16 : 16 MiB
  bh* WvT   = (bh*)(ws + (16u << 20));         // 1024 x 1024      :  2 MiB
  bh* W1T   = (bh*)(ws + (18u << 20));         // 2048 x 2048      :  8 MiB
  bh* W2T   = (bh*)(ws + (26u << 20));         // 4096 x 2048      : 16 MiB
  bh* Vt    = (bh*)(ws + (42u << 20));         // 1024 x 4096      :  8 MiB
  bh* hid   = (bh*)(ws + (50u << 20));         // 4096 x 2048      : 16 MiB
  bh* scr   = (bh*)(ws + (66u << 20));         // 4096 x 4096 bf16 : 32 MiB (exp scores)
  float* S  = (float*)(ws + (98u << 20));      // 1024 fp32 (4 KB)
  float* rowsum = (float*)(ws + (98u << 20) + 4096);  // 4096 fp32 (16 KB)

  hipError_t e = hipMemsetAsync(S, 0, 4096 + 4096 * sizeof(float), stream);
  (void)e;
  // D2: feat left half + colsum + all 3 weight transposes
  prep_and_transpose<<<dim3(512 + 1024 + 4096 + 8192), 256, 0, stream>>>(
      X, featb, S, Wv, W1, W2, WvT, W1T, W2T);
  // D3: Vt = (feat_left @ Wv + bv)^T  ||  loo -> feat right half
  gemm1_and_loo<<<dim3(512 + (TOK * DIM) / 1024), 256, 0, stream>>>(
      featb, WvT, bv, Vt, X, S, featb);
  // D4: hid = relu(feat @ W1 + b1)
  gemm_bt<128, true, false, false, bh><<<dim3(32 * (HID / 128)), 256, 0, stream>>>(
      featb, W1T, b1, hid, nullptr, 2 * DIM, 2 * DIM, 2 * DIM, HID);
  // D5: scr = exp(hid @ W2 + b2)  [unnormalized softmax numerator] + rowsum
  gemm_bt<128, false, false, true, bh><<<dim3(32 * (TOK / 128)), 256, 0, stream>>>(
      hid, W2T, b2, scr, rowsum, HID, HID, HID, TOK);
  // D6: out = (scr @ V) / rowsum  — fused, full-K, no partials
  gemm4_fused<<<dim3(512), 256, 0, stream>>>(scr, Vt, rowsum, out);
}

// Round 12
// 293.212 us; speedup vs baseline: 1.0566x; 1.0566x over previous
//
#include <hip/hip_runtime.h>
#include <hip/hip_bf16.h>

#define TOK 4096
#define DIM 1024
#define HID 2048
#define LN10K 9.210340371976184f

typedef __bf16 bh;
typedef __bf16 v8bf __attribute__((ext_vector_type(8)));
typedef float v4f __attribute__((ext_vector_type(4)));

typedef const __attribute__((address_space(1))) void* gvp;
typedef __attribute__((address_space(3))) void* svp;

__device__ __forceinline__ void gl_lds16(const bh* g, bh* s) {
  __builtin_amdgcn_global_load_lds((gvp)g, (svp)s, 16, 0, 0);
}

// Journal:
// r6:  XCD remap REGRESSED (FETCH 76->145MB). Raw id order already good.
// r8:  dispatch merge 8->6 = +10.7us (launch-gap theory CONFIRMED). BEST.
// r9:  transposes inside D3/D4 REGRESSED: extra blocks on the critical
//      path of serial dispatches. Reverted.
// r10: cooperative mega-kernel KILLED the harness (graph capture). Never.
// r11: byte-identical r8 re-run: 309.8 vs 297.1 us -> run-to-run noise
//      is +/-6-13us. Sub-10us single-run deltas are not trustworthy.
// r12: 64x64 vectorized weight transpose (float4 loads, 16B bf16 stores,
//      [64][65] LDS, <=2-way banks) replacing 32x32 scalar version
//      (2B scattered stores, G13 violation). Blocks 13312 -> 3328.

// ---------------- GEMM body: C = act(A @ BT^T + bias), 16x16x32 MFMA -------
// m97-canonical config: 256 threads = 4 waves (2x2), block tile 128 x BN,
// BK=64, wave tile 64 x (BN/2), acc[4][BN/32] (64 VGPR at BN=128).
// Staging ledger: one gl_lds16 x 256 thr = 2048 bh = 32 rows of 64 cols;
// A tile 128 rows -> 4 calls; B tile BN rows -> BN/32 calls.
// EXPS: epilogue stores exp(score) + fp32 rowsum atomics.
// TROUT: epilogue transposes the 64x128 C-tile through LDS (reuses As)
// and stores coalesced 16B row segments.
template <int BN, bool RELU, bool TROUT, bool EXPS, typename OutT>
__device__ __forceinline__ void gemm_bt_body(int id,
                                             const bh* __restrict__ A,
                                             const bh* __restrict__ BT,
                                             const float* __restrict__ bias,
                                             OutT* __restrict__ C,
                                             float* __restrict__ rowsum,
                                             int K, int lda, int ldbt, int ldc) {
  constexpr int NT = BN / 32;          // n-frags per wave: 4 (BN=128) or 2 (BN=64)
  __shared__ bh As[128 * 64];          // 16 KB
  __shared__ bh Bs[BN * 64];           // 16 or 8 KB
  const int t = threadIdx.x;
  const int bm = (id & 31) * 128, bn = (id >> 5) * BN;

  const int srow = t >> 3;             // staging row-in-group 0..31
  const int c8 = ((t & 7) ^ (srow & 7)) * 8;
  const bh* gA = A + (size_t)(bm + srow) * lda + c8;
  const bh* gB = BT + (size_t)(bn + srow) * ldbt + c8;
  bh* sA = As + t * 8;
  bh* sB = Bs + t * 8;

  const int lane = t & 63, w = t >> 6;
  const int wm = (w >> 1) * 64, wn = (w & 1) * (BN / 2);
  const int lc = lane & 15, q = lane >> 4;

  v4f acc[4][NT] = {};
  for (int k0 = 0; k0 < K; k0 += 64) {
#pragma unroll
    for (int j = 0; j < 4; ++j)
      gl_lds16(gA + k0 + j * 32 * lda, sA + j * 2048);
#pragma unroll
    for (int j = 0; j < BN / 32; ++j)
      gl_lds16(gB + k0 + j * 32 * ldbt, sB + j * 2048);
    __syncthreads();
#pragma unroll
    for (int h = 0; h < 2; ++h) {
      const int off = ((h * 4 + q) ^ (lc & 7)) * 8;
      v8bf af[4], bfr[NT];
#pragma unroll
      for (int mt = 0; mt < 4; ++mt)
        af[mt] = *(const v8bf*)(As + (wm + mt * 16 + lc) * 64 + off);
#pragma unroll
      for (int nt = 0; nt < NT; ++nt)
        bfr[nt] = *(const v8bf*)(Bs + (wn + nt * 16 + lc) * 64 + off);
#pragma unroll
      for (int mt = 0; mt < 4; ++mt)
#pragma unroll
        for (int nt = 0; nt < NT; ++nt)
          acc[mt][nt] = __builtin_amdgcn_mfma_f32_16x16x32_bf16(af[mt], bfr[nt], acc[mt][nt], 0, 0, 0);
    }
    __syncthreads();
  }

  // C/D layout: col = lane&15, row = q*4 + r  (m89-verified)
  const int r4 = q * 4;
  if (EXPS) {
    float bbv[NT];
#pragma unroll
    for (int nt = 0; nt < NT; ++nt)
      bbv[nt] = bias ? bias[bn + wn + nt * 16 + lc] : 0.0f;
#pragma unroll
    for (int mt = 0; mt < 4; ++mt) {
#pragma unroll
      for (int r = 0; r < 4; ++r) {
        int row = bm + wm + mt * 16 + r4 + r;
        float rs = 0.0f;
#pragma unroll
        for (int nt = 0; nt < NT; ++nt) {
          float val = __expf(acc[mt][nt][r] + bbv[nt]);
          rs += val;
          C[(size_t)row * ldc + bn + wn + nt * 16 + lc] = (OutT)val;
        }
        rs += __shfl_xor(rs, 1);
        rs += __shfl_xor(rs, 2);
        rs += __shfl_xor(rs, 4);
        rs += __shfl_xor(rs, 8);
        if (lc == 0) atomicAdd(rowsum + row, rs);
      }
    }
  } else if (TROUT) {
    // transpose 64(col) x 128(row) tile through LDS (reuse As: 8192 bh),
    // then coalesced 16B stores: each output row = 256B contiguous.
    bh* trs = As;  // safe: k-loop ended with __syncthreads after all reads
#pragma unroll
    for (int mt = 0; mt < 4; ++mt) {
#pragma unroll
      for (int nt = 0; nt < NT; ++nt) {
        int cl = wn + nt * 16 + lc;          // 0..63 (BN=64)
        float bb = bias ? bias[bn + cl] : 0.0f;
#pragma unroll
        for (int r = 0; r < 4; ++r) {
          float val = acc[mt][nt][r] + bb;
          if (RELU) val = fmaxf(val, 0.0f);
          trs[cl * 128 + (wm + mt * 16 + r4 + r)] = (bh)val;
        }
      }
    }
    __syncthreads();
#pragma unroll
    for (int p = 0; p < 4; ++p) {
      int chunk = p * 256 + t;               // 0..1023 over 64x128 tile
      int vr = chunk >> 4, sc = chunk & 15;  // row 0..63, 16B seg 0..15
      *(v8bf*)((bh*)C + (size_t)(bn + vr) * ldc + bm + sc * 8) =
          *(const v8bf*)(trs + vr * 128 + sc * 8);
    }
  } else {
#pragma unroll
    for (int mt = 0; mt < 4; ++mt) {
      int row0 = bm + wm + mt * 16 + r4;
#pragma unroll
      for (int nt = 0; nt < NT; ++nt) {
        int col = bn + wn + nt * 16 + lc;
        float bb = bias ? bias[col] : 0.0f;
#pragma unroll
        for (int r = 0; r < 4; ++r) {
          float val = acc[mt][nt][r] + bb;
          if (RELU) val = fmaxf(val, 0.0f);
          C[(size_t)(row0 + r) * ldc + col] = (OutT)val;
        }
      }
    }
  }
}

template <int BN, bool RELU, bool TROUT, bool EXPS, typename OutT>
__global__ __launch_bounds__(256, 2) void gemm_bt(const bh* __restrict__ A,
                                                  const bh* __restrict__ BT,
                                                  const float* __restrict__ bias,
                                                  OutT* __restrict__ C,
                                                  float* __restrict__ rowsum,
                                                  int K, int lda, int ldbt, int ldc) {
  gemm_bt_body<BN, RELU, TROUT, EXPS, OutT>(blockIdx.x, A, BT, bias, C, rowsum,
                                            K, lda, ldbt, ldc);
}

// ---------------- D2: prep_x_colsum U transpose_all (one dispatch) ---------
// blocks 0..511: cast X -> feat left half + colsum(E) partial atomics.
// blocks 512..3839: 64x64 VECTORIZED transpose+cast tiles of Wv/W1/W2:
//   float4 loads (16B/lane), [64][65] f32 LDS tile (<=2-way banks both
//   sides), v8bf 16B coalesced stores (8 thr = 128B contiguous per row).
__global__ __launch_bounds__(256) void prep_and_transpose(
    const float* __restrict__ X, bh* __restrict__ featb, float* __restrict__ S,
    const float* __restrict__ Wv, const float* __restrict__ W1,
    const float* __restrict__ W2, bh* __restrict__ WvT, bh* __restrict__ W1T,
    bh* __restrict__ W2T) {
  int bid = blockIdx.x;
  if (bid < 512) {
    // prep_x_colsum (orig grid (2,256) flattened: bx=bid&1, by=bid>>1)
    int cp = (bid & 1) * 256 + threadIdx.x;     // column pair 0..511
    int c = cp * 2;
    int r0 = (bid >> 1) * 16;
    float inv_denom = __expf(-(float)c * (LN10K / (float)DIM));
    float s0 = 0.f, s1 = 0.f;
#pragma unroll 4
    for (int r = r0; r < r0 + 16; ++r) {
      float2 x = *(const float2*)(X + (size_t)r * DIM + c);
      float sn, cs;
      __sincosf((float)r * inv_denom, &sn, &cs);
      s0 += sn * x.x;
      s1 += cs * x.y;
      bh pair[2] = {(bh)x.x, (bh)x.y};
      *(ushort2*)(featb + (size_t)r * (2 * DIM) + c) = *(ushort2*)pair;
    }
    atomicAdd(&S[c], s0);
    atomicAdd(&S[c + 1], s1);
    return;
  }
  bid -= 512;
  const float* in; bh* out; int Ncol, R, bx, by;
  if (bid < 256)       { in = Wv; out = WvT; Ncol = DIM; R = DIM;      // 16x16
                         bx = bid & 15; by = bid >> 4; }
  else if (bid < 1280) { int b = bid - 256; in = W1; out = W1T;        // 32x32
                         Ncol = HID; R = 2 * DIM; bx = b & 31; by = b >> 5; }
  else                 { int b = bid - 1280; in = W2; out = W2T;       // 64x32
                         Ncol = TOK; R = HID; bx = b & 63; by = b >> 6; }
  __shared__ float tile[64][65];                // 16.6 KB; +1 pad
  const int t = threadIdx.x;
  const int nb = bx * 64, rb = by * 64;
  const int rr = t >> 4, c4 = (t & 15) * 4;
#pragma unroll
  for (int j = 0; j < 4; ++j) {
    float4 v = *(const float4*)(in + (size_t)(rb + rr + j * 16) * Ncol + nb + c4);
    tile[rr + j * 16][c4 + 0] = v.x;
    tile[rr + j * 16][c4 + 1] = v.y;
    tile[rr + j * 16][c4 + 2] = v.z;
    tile[rr + j * 16][c4 + 3] = v.w;
  }
  __syncthreads();
  const int n0 = t >> 3, r8 = (t & 7) * 8;
#pragma unroll
  for (int j = 0; j < 2; ++j) {
    int n = n0 + j * 32;
    bh pk[8];
#pragma unroll
    for (int k = 0; k < 8; ++k) pk[k] = (bh)tile[r8 + k][n];
    *(v8bf*)(out + (size_t)(nb + n) * R + rb + r8) = *(v8bf*)pk;
  }
}

// ---------------- D3: gemm1 (V^T) U prep_loo (one dispatch) ----------------
// blocks 0..511: Vt = (feat_left @ WvT^T + bv)^T  (reads featb LEFT half
// only: staging col = k0 + c8 + j-in-16B <= 1023; WvT from D2).
// blocks 512..4607: loo -> feat RIGHT half (reads S from D2). No overlap.
__global__ __launch_bounds__(256, 2) void gemm1_and_loo(
    const bh* __restrict__ featb, const bh* __restrict__ WvT,
    const float* __restrict__ bv, bh* __restrict__ Vt,
    const float* __restrict__ X, const float* __restrict__ S,
    bh* __restrict__ featb_w) {
  int bid = blockIdx.x;
  if (bid < 512) {
    gemm_bt_body<64, false, true, false, bh>(bid, featb, WvT, bv, Vt, nullptr,
                                             DIM, 2 * DIM, DIM, TOK);
    return;
  }
  // prep_loo
  size_t e4 = ((size_t)(bid - 512) * 256 + threadIdx.x) * 4;  // over TOK*DIM
  int r = (int)(e4 >> 10);
  int c = (int)(e4 & 1023);
  float4 x = *(const float4*)(X + e4);
  float4 s = *(const float4*)(S + c);
  float id0 = __expf(-(float)c * (LN10K / (float)DIM));
  float id1 = __expf(-(float)(c + 2) * (LN10K / (float)DIM));
  float sn0, cs0, sn1, cs1;
  __sincosf((float)r * id0, &sn0, &cs0);
  __sincosf((float)r * id1, &sn1, &cs1);
  const float inv = 1.0f / (float)(TOK - 1);
  bh outv[4];
  outv[0] = (bh)((s.x - sn0 * x.x) * inv);
  outv[1] = (bh)((s.y - cs0 * x.y) * inv);
  outv[2] = (bh)((s.z - sn1 * x.z) * inv);
  outv[3] = (bh)((s.w - cs1 * x.w) * inv);
  *(ushort4*)(featb_w + (size_t)r * (2 * DIM) + DIM + c) = *(ushort4*)outv;
}

// ---------------- gemm4_fused: out = (scr @ V) / rowsum, full-K ------------
// Tile 64x128, BK=64, K=4096. 256 thr = 4 waves (2Mx2N), wave tile 32x64,
// acc[2][4]. Grid 512 blocks = 2/CU. LDS 8KB A + 16KB B.
// Staging ledger: A tile 64 rows -> 2 calls; B tile 128 rows -> 4 calls.
__global__ __launch_bounds__(256, 2) void gemm4_fused(const bh* __restrict__ A,
                                                      const bh* __restrict__ BT,
                                                      const float* __restrict__ rowsum,
                                                      float* __restrict__ out) {
  __shared__ bh As[64 * 64];           // 8 KB
  __shared__ bh Bs[128 * 64];          // 16 KB
  const int t = threadIdx.x;
  const int id = blockIdx.x;           // 512 blocks
  const int bm = (id & 63) * 64, bn = (id >> 6) * 128;

  const int sr = t >> 3;               // 0..31
  const int c8 = ((t & 7) ^ (sr & 7)) * 8;
  const bh* gA = A + (size_t)(bm + sr) * TOK + c8;
  const bh* gB = BT + (size_t)(bn + sr) * TOK + c8;
  bh* sA = As + t * 8;
  bh* sB = Bs + t * 8;

  const int lane = t & 63, w = t >> 6;
  const int wm = (w >> 1) * 32, wn = (w & 1) * 64;
  const int lc = lane & 15, q = lane >> 4;

  v4f acc[2][4] = {};
  for (int k0 = 0; k0 < TOK; k0 += 64) {
#pragma unroll
    for (int j = 0; j < 2; ++j)
      gl_lds16(gA + k0 + (size_t)(j * 32) * TOK, sA + j * 2048);
#pragma unroll
    for (int j = 0; j < 4; ++j)
      gl_lds16(gB + k0 + (size_t)(j * 32) * TOK, sB + j * 2048);
    __syncthreads();
#pragma unroll
    for (int h = 0; h < 2; ++h) {
      const int off = ((h * 4 + q) ^ (lc & 7)) * 8;
      v8bf af[2], bfr[4];
#pragma unroll
      for (int mt = 0; mt < 2; ++mt)
        af[mt] = *(const v8bf*)(As + (wm + mt * 16 + lc) * 64 + off);
#pragma unroll
      for (int nt = 0; nt < 4; ++nt)
        bfr[nt] = *(const v8bf*)(Bs + (wn + nt * 16 + lc) * 64 + off);
#pragma unroll
      for (int mt = 0; mt < 2; ++mt)
#pragma unroll
        for (int nt = 0; nt < 4; ++nt)
          acc[mt][nt] = __builtin_amdgcn_mfma_f32_16x16x32_bf16(af[mt], bfr[nt], acc[mt][nt], 0, 0, 0);
    }
    __syncthreads();
  }

  const int r4 = q * 4;
#pragma unroll
  for (int mt = 0; mt < 2; ++mt) {
#pragma unroll
    for (int r = 0; r < 4; ++r) {
      int row = bm + wm + mt * 16 + r4 + r;
      float inv = 1.0f / rowsum[row];
#pragma unroll
      for (int nt = 0; nt < 4; ++nt)
        out[(size_t)row * DIM + bn + wn + nt * 16 + lc] = acc[mt][nt][r] * inv;
    }
  }
}

extern "C" void kernel_launch(void* const* d_in, const int* in_sizes, int n_in,
                              void* d_out, int out_size, void* d_ws, size_t ws_size,
                              hipStream_t stream) {
  (void)in_sizes; (void)n_in; (void)out_size; (void)ws_size;
  const float* X  = (const float*)d_in[0];
  // d_in[1] = mask, unused by the module
  const float* Wv = (const float*)d_in[2];
  const float* bv = (const float*)d_in[3];
  const float* W1 = (const float*)d_in[4];
  const float* b1 = (const float*)d_in[5];
  const float* W2 = (const float*)d_in[6];
  const float* b2 = (const float*)d_in[7];
  float* out = (float*)d_out;

  char* ws = (char*)d_ws;
  bh* featb = (bh*)(ws);                       // 4096 x 2048 bf16 : 16 MiB
  bh* WvT   = (bh*)(ws + (16u << 20));         // 1024 x 1024      :  2 MiB
  bh* W1T   = (bh*)(ws + (18u << 20));         // 2048 x 2048      :  8 MiB
  bh* W2T   = (bh*)(ws + (26u << 20));         // 4096 x 2048      : 16 MiB
  bh* Vt    = (bh*)(ws + (42u << 20));         // 1024 x 4096      :  8 MiB
  bh* hid   = (bh*)(ws + (50u << 20));         // 4096 x 2048      : 16 MiB
  bh* scr   = (bh*)(ws + (66u << 20));         // 4096 x 4096 bf16 : 32 MiB (exp scores)
  float* S  = (float*)(ws + (98u << 20));      // 1024 fp32 (4 KB)
  float* rowsum = (float*)(ws + (98u << 20) + 4096);  // 4096 fp32 (16 KB)

  hipError_t e = hipMemsetAsync(S, 0, 4096 + 4096 * sizeof(float), stream);
  (void)e;
  // D2: feat left half + colsum + all 3 weight transposes (64x64 vectorized)
  prep_and_transpose<<<dim3(512 + 256 + 1024 + 2048), 256, 0, stream>>>(
      X, featb, S, Wv, W1, W2, WvT, W1T, W2T);
  // D3: Vt = (feat_left @ Wv + bv)^T  ||  loo -> feat right half
  gemm1_and_loo<<<dim3(512 + (TOK * DIM) / 1024), 256, 0, stream>>>(
      featb, WvT, bv, Vt, X, S, featb);
  // D4: hid = relu(feat @ W1 + b1)
  gemm_bt<128, true, false, false, bh><<<dim3(32 * (HID / 128)), 256, 0, stream>>>(
      featb, W1T, b1, hid, nullptr, 2 * DIM, 2 * DIM, 2 * DIM, HID);
  // D5: scr = exp(hid @ W2 + b2)  [unnormalized softmax numerator] + rowsum
  gemm_bt<128, false, false, true, bh><<<dim3(32 * (TOK / 128)), 256, 0, stream>>>(
      hid, W2T, b2, scr, rowsum, HID, HID, HID, TOK);
  // D6: out = (scr @ V) / rowsum  — fused, full-K, no partials
  gemm4_fused<<<dim3(512), 256, 0, stream>>>(scr, Vt, rowsum, out);
}